// Round 1
// baseline (884.731 us; speedup 1.0000x reference)
//
#include <hip/hip_runtime.h>

#define D 128

__global__ __launch_bounds__(256) void transd_kernel(
    const int* __restrict__ head,
    const int* __restrict__ relation,
    const int* __restrict__ tail,
    const float* __restrict__ ent_emb,
    const float* __restrict__ ent_map_emb,
    const float* __restrict__ rel_emb,
    const float* __restrict__ rel_map_emb,
    float* __restrict__ out,
    int B)
{
    // 32 lanes per batch element; each lane handles 4 consecutive floats (float4).
    int tid  = blockIdx.x * blockDim.x + threadIdx.x;
    int elem = tid >> 5;   // batch element
    int sub  = tid & 31;   // lane within the 32-lane group (column = sub*4)
    if (elem >= B) return;

    int h_idx = head[elem];
    int t_idx = tail[elem];
    int r_idx = relation[elem];

    const float4* h_row  = (const float4*)(ent_emb     + (size_t)h_idx * D);
    const float4* hp_row = (const float4*)(ent_map_emb + (size_t)h_idx * D);
    const float4* t_row  = (const float4*)(ent_emb     + (size_t)t_idx * D);
    const float4* tp_row = (const float4*)(ent_map_emb + (size_t)t_idx * D);
    const float4* r_row  = (const float4*)(rel_emb     + (size_t)r_idx * D);
    const float4* rp_row = (const float4*)(rel_map_emb + (size_t)r_idx * D);

    float4 h4  = h_row[sub];
    float4 hp4 = hp_row[sub];
    float4 t4  = t_row[sub];
    float4 tp4 = tp_row[sub];
    float4 r4  = r_row[sub];
    float4 rp4 = rp_row[sub];

    // partial dots: hp.h and tp.t ; combine into one reduction (dh - dt)
    float s = (h4.x * hp4.x + h4.y * hp4.y + h4.z * hp4.z + h4.w * hp4.w)
            - (t4.x * tp4.x + t4.y * tp4.y + t4.z * tp4.z + t4.w * tp4.w);

    // butterfly reduce over the 32-lane half-wave (masks < 32 stay in-half on wave64)
    #pragma unroll
    for (int m = 1; m < 32; m <<= 1)
        s += __shfl_xor(s, m, 64);

    float4 o;
    o.x = h4.x - t4.x + r4.x + rp4.x * s;
    o.y = h4.y - t4.y + r4.y + rp4.y * s;
    o.z = h4.z - t4.z + r4.z + rp4.z * s;
    o.w = h4.w - t4.w + r4.w + rp4.w * s;

    float4* out_row = (float4*)(out + (size_t)elem * D);
    out_row[sub] = o;
}

extern "C" void kernel_launch(void* const* d_in, const int* in_sizes, int n_in,
                              void* d_out, int out_size, void* d_ws, size_t ws_size,
                              hipStream_t stream) {
    const int*   head        = (const int*)d_in[0];
    const int*   relation    = (const int*)d_in[1];
    const int*   tail        = (const int*)d_in[2];
    const float* ent_emb     = (const float*)d_in[3];
    const float* ent_map_emb = (const float*)d_in[4];
    const float* rel_emb     = (const float*)d_in[5];
    const float* rel_map_emb = (const float*)d_in[6];
    float* out = (float*)d_out;

    int B = in_sizes[0];
    // 32 threads per element, 256-thread blocks -> 8 elements per block
    int blocks = (B + 7) / 8;
    transd_kernel<<<blocks, 256, 0, stream>>>(head, relation, tail,
                                              ent_emb, ent_map_emb,
                                              rel_emb, rel_map_emb,
                                              out, B);
}